// Round 1
// 324.136 us; speedup vs baseline: 1.0763x; 1.0763x over previous
//
#include <hip/hip_runtime.h>
#include <stdint.h>

#define T_ 128

typedef int v4i __attribute__((ext_vector_type(4)));

// ---------------------------------------------------------------------------
// prep 1: static B-fragments for mfma_i32_16x16x64_i8, biased i8 (byte-128).
// Fragment mf = (tau*5 + kappa)*2 + h. Lane l holds n = l&15,
// k-slots kin = (l>>4)*16 + 4r + b — identical slot->k map as scan's A, so
// any HW k-permutation cancels in the dot.
__global__ void prep_bfrag(const int* __restrict__ sc, uint4* __restrict__ bf) {
  int gid = blockIdx.x * 256 + threadIdx.x;
  if (gid >= 160 * 64) return;
  int mf = gid >> 6, l = gid & 63;
  int tau = mf / 10, rem = mf % 10;
  int kap = rem >> 1, h = rem & 1;
  int j = 16 * tau + (l & 15);
  int kinb = (l >> 4) * 16;
  unsigned wout[4];
#pragma unroll
  for (int r = 0; r < 4; ++r) {
    unsigned wrd = 0;
#pragma unroll
    for (int be = 0; be < 4; ++be) {
      int kin = kinb + 4 * r + be;
      int col = (kap == 0) ? kin : 64 + ((kap - 1) << 6) + kin;
      unsigned c = (unsigned)sc[j * 320 + col];
      unsigned byte = (h ? (c >> 8) : c) & 0xFFu;
      byte = (byte - 128u) & 0xFFu;
      wrd |= byte << (8 * be);
    }
    wout[r] = wrd;
  }
  bf[gid] = make_uint4(wout[0], wout[1], wout[2], wout[3]);
}

// prep 2: window bits packed to u64 per (b,t)
__global__ void prep_wbits(const int* __restrict__ bits,
                           unsigned long long* __restrict__ wb) {
  int gid = blockIdx.x * 256 + threadIdx.x;
  int wv = gid >> 6, lane = gid & 63;
  unsigned long long m = __ballot(bits[gid] != 0);
  if (lane == 0) wb[wv] = m;
}

// prep 3: bitpack (state_mem >= 0.5) -> 2 MiB table (L2-resident for scan)
__global__ void prep_bitpack(const float* __restrict__ sm,
                             unsigned long long* __restrict__ packed) {
  int base = blockIdx.x * (256 * 32) + threadIdx.x;
  int lane = threadIdx.x & 63;
#pragma unroll 1
  for (int it = 0; it < 32; ++it) {
    int idx = base + it * 256;
    float v = sm[idx];
    unsigned long long m = __ballot(v >= 0.5f);
    if (lane == 0) packed[idx >> 6] = m;
  }
}

// ---------------------------------------------------------------------------
// per-lane expand of a 16-bit slice into an i8 {0,1} A-fragment (window only)
static __device__ __forceinline__ v4i expand16(unsigned b16) {
  v4i a;
#pragma unroll
  for (int r = 0; r < 4; ++r) {
    unsigned nib = (b16 >> (4 * r)) & 0xFu;
    a[r] = (int)((nib * 0x00204081u) & 0x01010101u);
  }
  return a;
}

// ---------------------------------------------------------------------------
// scan + heads: 1 block per batch row, 4 waves of 64 (1 wave/SIMD — the scan
// is latency-bound; lockstep wave pairs only added contention). Wave w owns
// N-tiles {4w..4w+3} = state outputs j in [64w, 64w+64) = state CHUNK w.
// Each lane gathers exactly one bit (j = 64w+l) and writes it as an i8 byte
// into the double-buffered LDS table ab[]; next step's A-fragments are plain
// broadcast ds_read_b128 from ab — no per-lane bit expansion in the loop.
__global__ __launch_bounds__(256, 1) void scan_heads(
    const uint4* __restrict__ bfrag,
    const unsigned long long* __restrict__ wbits,
    const unsigned* __restrict__ packed32,
    const int* __restrict__ head_conn,
    const int* __restrict__ head_coeffs,
    const float* __restrict__ head_mem,
    float* __restrict__ out) {
  __shared__ __align__(16) unsigned char ab[2][256];   // state bits as i8 bytes
  __shared__ __align__(16) unsigned mcnt[2][4];        // per-chunk popcounts
  const int tid = threadIdx.x;
  const int b = blockIdx.x;
  const int w = tid >> 6, l = tid & 63;
  const int qq = l >> 4;        // k-slot group of this lane (and local tile id)
  const int j = 64 * w + l;     // the state output this lane gathers

  // one-time: 40 static B-fragments (tiles 4w..4w+3) into registers
  v4i bf[4][5][2];
#pragma unroll
  for (int i = 0; i < 4; ++i)
#pragma unroll
    for (int k = 0; k < 5; ++k)
#pragma unroll
      for (int h = 0; h < 2; ++h) {
        int mf = ((4 * w + i) * 5 + k) * 2 + h;
        bf[i][k][h] = __builtin_bit_cast(v4i, bfrag[mf * 64 + l]);
      }

  // state0 = 0: zero the initial byte table + counts
  ab[0][tid] = (unsigned char)0;
  if (tid < 4) mcnt[0][tid] = 0u;

  unsigned long long wcur = wbits[b * 128];
  const unsigned* pkrow = packed32 + ((size_t)j << 11);  // this lane's j-row

  // pre-init accumulators with the t=0 window (k=0) contribution
  v4i acc[4][2];
  {
    v4i aw = expand16((unsigned)((wcur >> (16 * qq)) & 0xFFFFu));
    v4i z = (v4i){0, 0, 0, 0};
#pragma unroll
    for (int i = 0; i < 4; ++i)
#pragma unroll
      for (int h = 0; h < 2; ++h)
        acc[i][h] = __builtin_amdgcn_mfma_i32_16x16x64_i8(aw, bf[i][0][h], z, 0, 0, 0);
  }
  __syncthreads();

  int cur = 0;
#pragma unroll 1
  for (int t = 0; t < T_; ++t) {
    int tn = (t + 1 < T_) ? t + 1 : t;
    unsigned long long wnext = wbits[b * 128 + tn];  // issued early, used late

    // bias fixup: NB = popcount of all 320 input bits
    uint4 cz = *((const uint4*)&mcnt[cur][0]);
    unsigned NB = cz.x + cz.y + cz.z + cz.w + (unsigned)__popcll(wcur);

    // state-chunk A fragments straight from the byte table (broadcast reads)
#pragma unroll
    for (int c = 0; c < 4; ++c) {
      v4i a = *((const v4i*)&ab[cur][64 * c + 16 * qq]);
      acc[0][0] = __builtin_amdgcn_mfma_i32_16x16x64_i8(a, bf[0][c + 1][0], acc[0][0], 0, 0, 0);
      acc[0][1] = __builtin_amdgcn_mfma_i32_16x16x64_i8(a, bf[0][c + 1][1], acc[0][1], 0, 0, 0);
      acc[1][0] = __builtin_amdgcn_mfma_i32_16x16x64_i8(a, bf[1][c + 1][0], acc[1][0], 0, 0, 0);
      acc[1][1] = __builtin_amdgcn_mfma_i32_16x16x64_i8(a, bf[1][c + 1][1], acc[1][1], 0, 0, 0);
      acc[2][0] = __builtin_amdgcn_mfma_i32_16x16x64_i8(a, bf[2][c + 1][0], acc[2][0], 0, 0, 0);
      acc[2][1] = __builtin_amdgcn_mfma_i32_16x16x64_i8(a, bf[2][c + 1][1], acc[2][1], 0, 0, 0);
      acc[3][0] = __builtin_amdgcn_mfma_i32_16x16x64_i8(a, bf[3][c + 1][0], acc[3][0], 0, 0, 0);
      acc[3][1] = __builtin_amdgcn_mfma_i32_16x16x64_i8(a, bf[3][c + 1][1], acc[3][1], 0, 0, 0);
    }

    // epilogue: lane l reads output (tile = l>>4, n = l&15) = state j = 64w+l
    unsigned corr = (NB * 32896u) & 0xFFFFu;  // 128*257 bias fixup
    unsigned lo01 = (l & 16) ? (unsigned)acc[1][0][0] : (unsigned)acc[0][0][0];
    unsigned lo23 = (l & 16) ? (unsigned)acc[3][0][0] : (unsigned)acc[2][0][0];
    unsigned hi01 = (l & 16) ? (unsigned)acc[1][1][0] : (unsigned)acc[0][1][0];
    unsigned hi23 = (l & 16) ? (unsigned)acc[3][1][0] : (unsigned)acc[2][1][0];
    unsigned lo = (l & 32) ? lo23 : lo01;
    unsigned hi = (l & 32) ? hi23 : hi01;
    unsigned ad = (lo + (hi << 8) + corr) & 0xFFFFu;

    // self-gather: one bit per lane, 256 per block
    unsigned word = pkrow[ad >> 5];

    // fill gather latency: next step's window-chunk MFMAs into fresh accs
    {
      v4i aw = expand16((unsigned)((wnext >> (16 * qq)) & 0xFFFFu));
      v4i z = (v4i){0, 0, 0, 0};
#pragma unroll
      for (int i = 0; i < 4; ++i)
#pragma unroll
        for (int h = 0; h < 2; ++h)
          acc[i][h] = __builtin_amdgcn_mfma_i32_16x16x64_i8(aw, bf[i][0][h], z, 0, 0, 0);
    }

    unsigned bitv = (word >> (ad & 31)) & 1u;
    unsigned long long mq = __ballot(bitv != 0u);
    int nxt = cur ^ 1;
    ab[nxt][j] = (unsigned char)bitv;                    // byte {0,1} in place
    if (l == 0) mcnt[nxt][w] = (unsigned)__popcll(mq);   // chunk popcount

    __syncthreads();
    cur = nxt;
    wcur = wnext;
  }

  // ---- heads (wave 0): only the selected head per batch row
  if (w == 0) {
    int h = (int)((((wcur >> 61) & 1) << 2) | (((wcur >> 62) & 1) << 1) |
                  ((wcur >> 63) & 1));
    int ho = h * 64 + l;
    const int4* cn4 = (const int4*)(head_conn + ho * 8);
    const int4* cf4 = (const int4*)(head_coeffs + ho * 8);
    int4 cna = cn4[0], cnb = cn4[1];
    int4 cfa = cf4[0], cfb = cf4[1];
    int cns[8] = {cna.x, cna.y, cna.z, cna.w, cnb.x, cnb.y, cnb.z, cnb.w};
    int cfs[8] = {cfa.x, cfa.y, cfa.z, cfa.w, cfb.x, cfb.y, cfb.z, cfb.w};
    unsigned addr = 0;
#pragma unroll
    for (int k = 0; k < 8; ++k) {
      addr += (unsigned)ab[cur][cns[k]] * (unsigned)cfs[k];
    }
    addr &= 0xFFFFu;
    out[b * 64 + l] = head_mem[((size_t)ho << 16) + addr];
  }
}

extern "C" void kernel_launch(void* const* d_in, const int* in_sizes, int n_in,
                              void* d_out, int out_size, void* d_ws, size_t ws_size,
                              hipStream_t stream) {
  const int*   bits         = (const int*)d_in[0];
  const int*   state_coeffs = (const int*)d_in[1];
  const float* state_mem    = (const float*)d_in[2];
  const int*   head_conn    = (const int*)d_in[3];
  const int*   head_coeffs  = (const int*)d_in[4];
  const float* head_mem     = (const float*)d_in[5];
  float* out = (float*)d_out;

  char* ws = (char*)d_ws;
  uint4*              bfrag  = (uint4*)ws;                             // 160 KiB
  unsigned long long* wbits  = (unsigned long long*)(ws + (160 << 10)); // 128 KiB
  unsigned*           packed = (unsigned*)(ws + (288 << 10));          // 2 MiB

  prep_bfrag<<<40, 256, 0, stream>>>(state_coeffs, bfrag);
  prep_wbits<<<4096, 256, 0, stream>>>(bits, wbits);
  prep_bitpack<<<2048, 256, 0, stream>>>(state_mem, (unsigned long long*)packed);
  scan_heads<<<128, 256, 0, stream>>>(bfrag, wbits, packed,
                                      head_conn, head_coeffs, head_mem, out);
}